// Round 2
// baseline (905.788 us; speedup 1.0000x reference)
//
#include <hip/hip_runtime.h>
#include <math.h>

// Problem constants
#define BATCH 256
#define IC    1152
#define EDIM  8
#define NC    10
#define DV    16

// Tiling
#define ITILE 8                    // i's per block
#define NB    32                   // b's per block (looped)
#define NTHREADS 256               // 8 i * 2 c-halves * 16 d
#define ICHUNKS (IC / ITILE)       // 144
#define BCHUNKS (BATCH / NB)       // 8
#define SCD (NC * DV)              // 160
#define SPART_STRIDE (BATCH * SCD) // 40960 floats per i-chunk slab

// ---------------------------------------------------------------------------
// DPP-based 16-lane (row) sum reduce: xor1,xor2 via quad_perm, then
// half_mirror (== xor4 once quads are uniform) and row_mirror (== xor8).
// All VALU — no DS pipe, no lgkmcnt waits.
// ---------------------------------------------------------------------------
template<int CTRL>
__device__ __forceinline__ float dpp_add(float x) {
    int r = __builtin_amdgcn_update_dpp(0, __float_as_int(x), CTRL, 0xF, 0xF, true);
    return x + __int_as_float(r);
}
__device__ __forceinline__ float row_reduce16(float x) {
    x = dpp_add<0xB1>(x);   // quad_perm [1,0,3,2] : xor 1
    x = dpp_add<0x4E>(x);   // quad_perm [2,3,0,1] : xor 2
    x = dpp_add<0x141>(x);  // row_half_mirror     : xor 4 (quads uniform)
    x = dpp_add<0x140>(x);  // row_mirror          : xor 8 (octs uniform)
    return x;
}

// ---------------------------------------------------------------------------
// Main fused kernel. Thread (il, ch, d): tid = il*32 + ch*16 + d.
// Each thread holds W[i, c, d, 0:8] for its 5 c's in registers, loops over
// 32 batch elements recomputing u_hat. s-partials accumulate into LDS via
// ds_add_f32 atomics (no barriers inside the loop), flushed coalesced at end.
// MODE 1: c = softmax(bias)                       -> s1 partials
// MODE 2: b2 = (u.v1) + 2*bias (stored), softmax  -> s2 partials
// MODE 3: b3 = (u.v2) + b2 + bias, softmax        -> s3 partials
// ---------------------------------------------------------------------------
template<int MODE>
__global__ __launch_bounds__(NTHREADS)
void caps_main(const float* __restrict__ x,
               const float* __restrict__ W,
               const float* __restrict__ bias,
               const float* __restrict__ v_in,
               float* __restrict__ b2,
               float* __restrict__ s_part)
{
    __shared__ float sx[NB][ITILE * EDIM];   // 8 KB
    __shared__ float s_acc[NB][SCD];         // 20 KB

    const int tid = threadIdx.x;
    const int d   = tid & 15;
    const int ch  = (tid >> 4) & 1;
    const int il  = tid >> 5;                // 0..7
    const int icb = blockIdx.x;              // 0..143
    const int bcb = blockIdx.y;              // 0..7
    const int i0  = icb * ITILE;
    const int b0  = bcb * NB;
    const int i   = i0 + il;

    // ---- zero the LDS s accumulator (5120 floats) ----
    {
        float4* sa = (float4*)&s_acc[0][0];
        #pragma unroll
        for (int j = 0; j < 5; ++j)
            sa[tid + j * NTHREADS] = make_float4(0.f, 0.f, 0.f, 0.f);
    }
    // ---- stage x slice into LDS (coalesced float4) ----
    {
        const float4* xg = (const float4*)x;
        float4* xs = (float4*)&sx[0][0];
        #pragma unroll
        for (int f = tid; f < NB * ITILE * EDIM / 4; f += NTHREADS) {
            int bb = f >> 4;
            int w  = f & 15;
            xs[f] = xg[(size_t)(b0 + bb) * (IC * EDIM / 4) + i0 * (EDIM / 4) + w];
        }
    }

    // ---- W fragment + bias into registers ----
    float4 w4[5][2];
    float  bv[5];
    const float4* Wg = (const float4*)W;
    #pragma unroll
    for (int k = 0; k < 5; ++k) {
        int c = ch * 5 + k;
        size_t base = ((size_t)(i * NC + c) * DV + d) * 2;
        w4[k][0] = Wg[base];
        w4[k][1] = Wg[base + 1];
        bv[k]    = bias[i * NC + c];
    }

    float cw[5];
    if (MODE == 1) {
        // softmax(bias[i,:]) — batch-independent, once per thread
        float mx = fmaxf(fmaxf(fmaxf(bv[0], bv[1]), fmaxf(bv[2], bv[3])), bv[4]);
        mx = fmaxf(mx, __shfl_xor(mx, 16));
        float ssum = 0.f, ex[5];
        #pragma unroll
        for (int k = 0; k < 5; ++k) { ex[k] = __expf(bv[k] - mx); ssum += ex[k]; }
        ssum += __shfl_xor(ssum, 16);
        float inv = 1.0f / ssum;
        #pragma unroll
        for (int k = 0; k < 5; ++k) cw[k] = ex[k] * inv;
    }

    __syncthreads();

    const int vbase = ch * 80 + d;           // v[b, (ch*5+k)*16 + d] base
    const int accb  = ch * 80 + d;           // s_acc column base (k*16 stride)

    for (int bb = 0; bb < NB; ++bb) {
        const int b = b0 + bb;
        const float4 x0 = ((const float4*)&sx[bb][il * EDIM])[0];
        const float4 x1 = ((const float4*)&sx[bb][il * EDIM])[1];

        // u_hat[b, i, c_k, d]
        float u[5];
        #pragma unroll
        for (int k = 0; k < 5; ++k) {
            float acc = w4[k][0].x * x0.x;
            acc = fmaf(w4[k][0].y, x0.y, acc);
            acc = fmaf(w4[k][0].z, x0.z, acc);
            acc = fmaf(w4[k][0].w, x0.w, acc);
            acc = fmaf(w4[k][1].x, x1.x, acc);
            acc = fmaf(w4[k][1].y, x1.y, acc);
            acc = fmaf(w4[k][1].z, x1.z, acc);
            acc = fmaf(w4[k][1].w, x1.w, acc);
            u[k] = acc;
        }

        if (MODE != 1) {
            // agreement: sum over d via DPP (VALU only)
            const float* vb = v_in + (size_t)b * SCD + vbase;
            float t[5];
            #pragma unroll
            for (int k = 0; k < 5; ++k) t[k] = u[k] * vb[k * 16];
            #pragma unroll
            for (int k = 0; k < 5; ++k) t[k] = row_reduce16(t[k]);

            float br[5];
            if (MODE == 2) {
                #pragma unroll
                for (int k = 0; k < 5; ++k) br[k] = t[k] + 2.0f * bv[k];
                if (d == 0) {
                    float* bp = b2 + ((size_t)b * IC + i) * NC + ch * 5;
                    #pragma unroll
                    for (int k = 0; k < 5; ++k) bp[k] = br[k];
                }
            } else {
                const float* bp = b2 + ((size_t)b * IC + i) * NC + ch * 5;
                #pragma unroll
                for (int k = 0; k < 5; ++k) br[k] = t[k] + bp[k] + bv[k];
            }
            // softmax over 10 c's: 5 local + partner half via xor-16
            float mx = fmaxf(fmaxf(fmaxf(br[0], br[1]), fmaxf(br[2], br[3])), br[4]);
            mx = fmaxf(mx, __shfl_xor(mx, 16));
            float ssum = 0.f, ex[5];
            #pragma unroll
            for (int k = 0; k < 5; ++k) { ex[k] = __expf(br[k] - mx); ssum += ex[k]; }
            ssum += __shfl_xor(ssum, 16);
            float inv = 1.0f / ssum;
            #pragma unroll
            for (int k = 0; k < 5; ++k) cw[k] = ex[k] * inv;
        }

        // s contribution: LDS float atomics, no barrier needed
        #pragma unroll
        for (int k = 0; k < 5; ++k)
            atomicAdd(&s_acc[bb][accb + k * 16], cw[k] * u[k]);
    }

    __syncthreads();

    // ---- coalesced flush of block's s partials ----
    {
        const float4* sa = (const float4*)&s_acc[0][0];
        float4* sp = (float4*)&s_part[((size_t)icb * BATCH + b0) * SCD];
        #pragma unroll
        for (int j = 0; j < 5; ++j)
            sp[tid + j * NTHREADS] = sa[tid + j * NTHREADS];
    }
}

// ---------------------------------------------------------------------------
// Reduce s-partials over the 144 i-chunk slabs and apply squash.
// Block = 16 (b,c) groups x 16 d. Grid = 2560/16 = 160 blocks.
// ---------------------------------------------------------------------------
__global__ __launch_bounds__(256)
void caps_squash(const float* __restrict__ s_part, float* __restrict__ out)
{
    const int tid = threadIdx.x;
    const int bc  = blockIdx.x * 16 + (tid >> 4);
    const size_t off = (size_t)bc * DV + (tid & 15);

    float a[8] = {0.f, 0.f, 0.f, 0.f, 0.f, 0.f, 0.f, 0.f};
    #pragma unroll 2
    for (int ic = 0; ic < ICHUNKS; ic += 8) {
        #pragma unroll
        for (int j = 0; j < 8; ++j)
            a[j] += s_part[(size_t)(ic + j) * SPART_STRIDE + off];
    }
    float s = ((a[0] + a[1]) + (a[2] + a[3])) + ((a[4] + a[5]) + (a[6] + a[7]));

    float sq = row_reduce16(s * s);

    // scale = sq/(1+sq)/sqrt(sq+EPS), EPS = 1e-7 (matches reference)
    float scale = sq / ((1.0f + sq) * sqrtf(sq + 1e-7f));
    out[off] = scale * s;
}

// ---------------------------------------------------------------------------
extern "C" void kernel_launch(void* const* d_in, const int* in_sizes, int n_in,
                              void* d_out, int out_size, void* d_ws, size_t ws_size,
                              hipStream_t stream)
{
    const float* x    = (const float*)d_in[0];   // [256,1152,8]
    const float* W    = (const float*)d_in[1];   // [1152,10,16,8]
    const float* bias = (const float*)d_in[2];   // [1152,10]
    float* out = (float*)d_out;                  // [256,10,16]

    float* ws     = (float*)d_ws;
    float* s_part = ws;                                        // 5,898,240 f
    float* v      = s_part + (size_t)ICHUNKS * SPART_STRIDE;   // 40,960 f
    float* b2     = v + SPART_STRIDE;                          // 2,949,120 f
    // total ws use: ~35.5 MB (same as previous passing round)

    dim3 grid(ICHUNKS, BCHUNKS);  // 144 x 8 = 1152 blocks

    // iter 1
    caps_main<1><<<grid, NTHREADS, 0, stream>>>(x, W, bias, v, b2, s_part);
    caps_squash<<<160, 256, 0, stream>>>(s_part, v);
    // iter 2
    caps_main<2><<<grid, NTHREADS, 0, stream>>>(x, W, bias, v, b2, s_part);
    caps_squash<<<160, 256, 0, stream>>>(s_part, v);
    // final
    caps_main<3><<<grid, NTHREADS, 0, stream>>>(x, W, bias, v, b2, s_part);
    caps_squash<<<160, 256, 0, stream>>>(s_part, out);
}

// Round 3
// 203.755 us; speedup vs baseline: 4.4455x; 4.4455x over previous
//
#include <hip/hip_runtime.h>
#include <math.h>

// Problem constants
#define BATCH 256
#define IC    1152
#define EDIM  8
#define NC    10
#define DV    16

// Tiling
#define ITILE 8                    // i's per block (fixed by 256-thread mapping)
#define NB    16                   // b's per block (looped)
#define NTHREADS 256               // 8 i * 2 c-halves * 16 d
#define NWAVES 4
#define ICHUNKS (IC / ITILE)       // 144
#define BCHUNKS (BATCH / NB)       // 16
#define SCD (NC * DV)              // 160
#define SPART_STRIDE (BATCH * SCD) // 40960 floats per i-chunk slab

// ---------------------------------------------------------------------------
// DPP-based 16-lane (row) sum reduce — all VALU, no DS pipe.
// (HW-verified correct in round 2.)
// ---------------------------------------------------------------------------
template<int CTRL>
__device__ __forceinline__ float dpp_add(float x) {
    int r = __builtin_amdgcn_update_dpp(0, __float_as_int(x), CTRL, 0xF, 0xF, true);
    return x + __int_as_float(r);
}
__device__ __forceinline__ float row_reduce16(float x) {
    x = dpp_add<0xB1>(x);   // quad_perm [1,0,3,2] : xor 1
    x = dpp_add<0x4E>(x);   // quad_perm [2,3,0,1] : xor 2
    x = dpp_add<0x141>(x);  // row_half_mirror     : xor 4 (quads uniform)
    x = dpp_add<0x140>(x);  // row_mirror          : xor 8 (octs uniform)
    return x;
}

// ---------------------------------------------------------------------------
// Main fused kernel. tid = il*32 + ch*16 + d (il 0..7, ch 0..1, d 0..15).
// Each thread holds W[i, c, d, 0:8] for its 5 c's in registers and loops
// over 16 batch elements recomputing u_hat.
// s-partials: xor-32 i-pair reduce (1 DS op), then each WAVE writes its own
// LDS slab — NO in-loop barriers, NO atomics. One barrier + 4-way reduce at
// the end, coalesced flush to global s_part.
// MODE 1: c = softmax(bias)                       -> s1 partials
// MODE 2: b2 = (u.v1) + 2*bias (stored), softmax  -> s2 partials
// MODE 3: b3 = (u.v2) + b2 + bias, softmax        -> s3 partials
// ---------------------------------------------------------------------------
template<int MODE>
__global__ __launch_bounds__(NTHREADS)
void caps_main(const float* __restrict__ x,
               const float* __restrict__ W,
               const float* __restrict__ bias,
               const float* __restrict__ v_in,
               float* __restrict__ b2,
               float* __restrict__ s_part)
{
    __shared__ float sx[NB][ITILE * EDIM];   // 4 KB
    __shared__ float swv[NWAVES][NB][SCD];   // 40 KB — wave-private slabs

    const int tid = threadIdx.x;
    const int d   = tid & 15;
    const int ch  = (tid >> 4) & 1;
    const int il  = tid >> 5;                // 0..7
    const int wid = tid >> 6;                // 0..3
    const int icb = blockIdx.x;              // 0..143
    const int bcb = blockIdx.y;              // 0..15
    const int i0  = icb * ITILE;
    const int b0  = bcb * NB;
    const int i   = i0 + il;

    // ---- stage x slice into LDS: 256 float4, one per thread ----
    {
        const float4* xg = (const float4*)x;
        float4* xs = (float4*)&sx[0][0];
        int bb = tid >> 4;                   // 16 float4 per (b, i-tile) row
        int w  = tid & 15;
        xs[tid] = xg[(size_t)(b0 + bb) * (IC * EDIM / 4) + i0 * (EDIM / 4) + w];
    }

    // ---- W fragment + bias into registers ----
    float4 w4[5][2];
    float  bv[5];
    const float4* Wg = (const float4*)W;
    #pragma unroll
    for (int k = 0; k < 5; ++k) {
        int c = ch * 5 + k;
        size_t base = ((size_t)(i * NC + c) * DV + d) * 2;
        w4[k][0] = Wg[base];
        w4[k][1] = Wg[base + 1];
        bv[k]    = bias[i * NC + c];
    }

    float cw[5];
    if (MODE == 1) {
        // softmax(bias[i,:]) — batch-independent, once per thread
        float mx = fmaxf(fmaxf(fmaxf(bv[0], bv[1]), fmaxf(bv[2], bv[3])), bv[4]);
        mx = fmaxf(mx, __shfl_xor(mx, 16));
        float ssum = 0.f, ex[5];
        #pragma unroll
        for (int k = 0; k < 5; ++k) { ex[k] = __expf(bv[k] - mx); ssum += ex[k]; }
        ssum += __shfl_xor(ssum, 16);
        float inv = 1.0f / ssum;
        #pragma unroll
        for (int k = 0; k < 5; ++k) cw[k] = ex[k] * inv;
    }

    __syncthreads();

    #pragma unroll 2
    for (int bb = 0; bb < NB; ++bb) {
        const int b = b0 + bb;
        const float4 x0 = ((const float4*)&sx[bb][il * EDIM])[0];
        const float4 x1 = ((const float4*)&sx[bb][il * EDIM])[1];

        // u_hat[b, i, c_k, d]
        float u[5];
        #pragma unroll
        for (int k = 0; k < 5; ++k) {
            float acc = w4[k][0].x * x0.x;
            acc = fmaf(w4[k][0].y, x0.y, acc);
            acc = fmaf(w4[k][0].z, x0.z, acc);
            acc = fmaf(w4[k][0].w, x0.w, acc);
            acc = fmaf(w4[k][1].x, x1.x, acc);
            acc = fmaf(w4[k][1].y, x1.y, acc);
            acc = fmaf(w4[k][1].z, x1.z, acc);
            acc = fmaf(w4[k][1].w, x1.w, acc);
            u[k] = acc;
        }

        if (MODE != 1) {
            // agreement: sum over d via DPP (VALU only); v is L2-hot (160 KB)
            const float* vb = v_in + (size_t)b * SCD + ch * 80 + d;
            float t[5];
            #pragma unroll
            for (int k = 0; k < 5; ++k) t[k] = u[k] * vb[k * 16];
            #pragma unroll
            for (int k = 0; k < 5; ++k) t[k] = row_reduce16(t[k]);

            float br[5];
            if (MODE == 2) {
                #pragma unroll
                for (int k = 0; k < 5; ++k) br[k] = t[k] + 2.0f * bv[k];
                if (d == 0) {
                    float* bp = b2 + ((size_t)b * IC + i) * NC + ch * 5;
                    #pragma unroll
                    for (int k = 0; k < 5; ++k) bp[k] = br[k];
                }
            } else {
                const float* bp = b2 + ((size_t)b * IC + i) * NC + ch * 5;
                #pragma unroll
                for (int k = 0; k < 5; ++k) br[k] = t[k] + bp[k] + bv[k];
            }
            // softmax over 10 c's: 5 local + partner half via xor-16
            float mx = fmaxf(fmaxf(fmaxf(br[0], br[1]), fmaxf(br[2], br[3])), br[4]);
            mx = fmaxf(mx, __shfl_xor(mx, 16));
            float ssum = 0.f, ex[5];
            #pragma unroll
            for (int k = 0; k < 5; ++k) { ex[k] = __expf(br[k] - mx); ssum += ex[k]; }
            ssum += __shfl_xor(ssum, 16);
            float inv = 1.0f / ssum;
            #pragma unroll
            for (int k = 0; k < 5; ++k) cw[k] = ex[k] * inv;
        }

        // s contribution: i-pair reduce (xor 32), then wave-private LDS slab.
        float sval[5];
        #pragma unroll
        for (int k = 0; k < 5; ++k) sval[k] = cw[k] * u[k];
        #pragma unroll
        for (int k = 0; k < 5; ++k) sval[k] += __shfl_xor(sval[k], 32);
        if ((tid & 32) == 0) {
            #pragma unroll
            for (int k = 0; k < 5; ++k)
                swv[wid][bb][ch * 80 + k * 16 + d] = sval[k];
        }
    }

    __syncthreads();

    // ---- reduce the 4 wave slabs, coalesced flush to global ----
    #pragma unroll
    for (int r = 0; r < (NB * SCD) / NTHREADS; ++r) {   // 10 iterations
        int j  = tid + r * NTHREADS;
        int bb = j / SCD;
        int cd = j - bb * SCD;
        float s = (swv[0][bb][cd] + swv[1][bb][cd])
                + (swv[2][bb][cd] + swv[3][bb][cd]);
        s_part[((size_t)icb * BATCH + b0 + bb) * SCD + cd] = s;
    }
}

// ---------------------------------------------------------------------------
// Reduce s-partials over the 144 i-chunk slabs and apply squash.
// Block = 16 (b,c) groups x 16 d. Grid = 2560/16 = 160 blocks.
// ---------------------------------------------------------------------------
__global__ __launch_bounds__(256)
void caps_squash(const float* __restrict__ s_part, float* __restrict__ out)
{
    const int tid = threadIdx.x;
    const int bc  = blockIdx.x * 16 + (tid >> 4);
    const size_t off = (size_t)bc * DV + (tid & 15);

    float a[8] = {0.f, 0.f, 0.f, 0.f, 0.f, 0.f, 0.f, 0.f};
    #pragma unroll 2
    for (int ic = 0; ic < ICHUNKS; ic += 8) {
        #pragma unroll
        for (int j = 0; j < 8; ++j)
            a[j] += s_part[(size_t)(ic + j) * SPART_STRIDE + off];
    }
    float s = ((a[0] + a[1]) + (a[2] + a[3])) + ((a[4] + a[5]) + (a[6] + a[7]));

    float sq = row_reduce16(s * s);

    // scale = sq/(1+sq)/sqrt(sq+EPS), EPS = 1e-7 (matches reference)
    float scale = sq / ((1.0f + sq) * sqrtf(sq + 1e-7f));
    out[off] = scale * s;
}

// ---------------------------------------------------------------------------
extern "C" void kernel_launch(void* const* d_in, const int* in_sizes, int n_in,
                              void* d_out, int out_size, void* d_ws, size_t ws_size,
                              hipStream_t stream)
{
    const float* x    = (const float*)d_in[0];   // [256,1152,8]
    const float* W    = (const float*)d_in[1];   // [1152,10,16,8]
    const float* bias = (const float*)d_in[2];   // [1152,10]
    float* out = (float*)d_out;                  // [256,10,16]

    float* ws     = (float*)d_ws;
    float* s_part = ws;                                        // 5,898,240 f
    float* v      = s_part + (size_t)ICHUNKS * SPART_STRIDE;   // 40,960 f
    float* b2     = v + SPART_STRIDE;                          // 2,949,120 f
    // total ws use: ~35.5 MB (same as round 1, proven to fit)

    dim3 grid(ICHUNKS, BCHUNKS);  // 144 x 16 = 2304 blocks

    // iter 1
    caps_main<1><<<grid, NTHREADS, 0, stream>>>(x, W, bias, v, b2, s_part);
    caps_squash<<<160, 256, 0, stream>>>(s_part, v);
    // iter 2
    caps_main<2><<<grid, NTHREADS, 0, stream>>>(x, W, bias, v, b2, s_part);
    caps_squash<<<160, 256, 0, stream>>>(s_part, v);
    // final
    caps_main<3><<<grid, NTHREADS, 0, stream>>>(x, W, bias, v, b2, s_part);
    caps_squash<<<160, 256, 0, stream>>>(s_part, out);
}